// Round 8
// baseline (370.126 us; speedup 1.0000x reference)
//
#include <hip/hip_runtime.h>
#include <cstdint>
#include <cstddef>

// ---------------------------------------------------------------------------
// GCN: h = elu(D^-1/2 (A+I) D^-1/2 (h W) + b) x3, mean-pool, MLP head.
// R21: attack the invisible 166us pre-chain + gather MLP.
//  (a) scatter takes the side jobs (WT cvt, pool zero, zero rows) AND builds
//      deg via per-edge global atomics.
//  (b) build+gemm1 fused into one kernel: build blocks read hist from deg
//      (deletes one full ebuf pass + 1.6M LDS atomics), gemm blocks run
//      layer-1 MFMA concurrently with dn = rsqrt(deg+1) computed locally.
//  (c) gather inner loop 8 -> 16 rows in flight (R18 loop minus the perm
//      that poisoned that measurement): 20 waves/CU x 8 outstanding vs
//      ~300cy L2 latency was marginal; 16 doubles it.
// R20 ledger: zero-pad tails worked (57.2->51.3, predicted 52-54).
// ---------------------------------------------------------------------------

#define SUBCAP 512   // per-(bucket,XCD) capacity: mean 256, +16 sigma
#define CSRCAP 4608  // per-bucket csr region: 4096 max edges + ceil4 padding
#define TILE 4096    // edges per scatter block

typedef __attribute__((ext_vector_type(8))) short short8;   // 8 bf16 = 4 VGPRs
typedef __attribute__((ext_vector_type(4))) float f32x4;
typedef __attribute__((ext_vector_type(2))) _Float16 h16x2; // packed f16 pair

__device__ __forceinline__ float bf2f(uint32_t u) {
  return __uint_as_float(u << 16);
}
__device__ __forceinline__ uint32_t f2bf(float f) {  // round-to-nearest-even
  uint32_t x = __float_as_uint(f);
  return (x + 0x7FFFu + ((x >> 16) & 1u)) >> 16;
}

union H16 { _Float16 h; uint16_t u; };
union H2U { h16x2 h; uint32_t u; };

// f32 -> e5m2 byte (RNE via f16 then RNE-truncate mantissa to 2 bits)
__device__ __forceinline__ uint32_t f2e5m2(float f) {
  f = fminf(fmaxf(f, -30000.f), 30000.f);
  H16 cv;
  cv.h = (_Float16)f;
  uint32_t h = cv.u;
  uint32_t r = h + 0x7Fu + ((h >> 8) & 1u);
  return (r >> 8) & 0xFFu;
}

// e5m2 byte -> f32 (exact: e5m2 is truncated f16)
__device__ __forceinline__ float e5m2f(uint32_t b) {
  H16 cv;
  cv.u = (uint16_t)(b << 8);
  return (float)cv.h;
}

// ---------------- CSR build ----------------

// Block-aggregated, XCD-partitioned scatter. 4096 edges/block. (R10)
// R21: + side jobs (WT cvt, pool zero, zero rows) + per-edge deg atomic.
__global__ __launch_bounds__(256) void bucket_scatter(const int* __restrict__ src,
                                                      const int* __restrict__ dst,
                                                      int* __restrict__ bcur,
                                                      uint32_t* __restrict__ ebuf,
                                                      int* __restrict__ deg,
                                                      const float* __restrict__ W1,
                                                      const float* __restrict__ W2,
                                                      const float* __restrict__ W3,
                                                      uint16_t* __restrict__ WT,
                                                      float* __restrict__ pool,
                                                      uint32_t* __restrict__ z0,
                                                      uint32_t* __restrict__ z1,
                                                      int nE, int nbuk) {
  uint32_t xcc;
  asm("s_getreg_b32 %0, hwreg(HW_REG_XCC_ID)" : "=s"(xcc));  // 0..7, wave-uniform
  __shared__ int lhist[1024];
  __shared__ int gbase[1024];
  int t = threadIdx.x;
  int G = (int)gridDim.x * 256;

  // Side jobs: W1,W2,W3 fp32 [k][nn] -> WT bf16 [w][nn][k]; zero pool; zero rows
  for (int id = (int)blockIdx.x * 256 + t; id < 3 * 16384; id += G) {
    int w = id >> 14;
    int rem = id & 16383;
    int k = rem >> 7, nn = rem & 127;
    const float* W = (w == 0) ? W1 : ((w == 1) ? W2 : W3);
    WT[w * 16384 + nn * 128 + k] = (uint16_t)f2bf(W[k * 128 + nn]);
  }
  for (int id = (int)blockIdx.x * 256 + t; id < 64 * 128; id += G) pool[id] = 0.f;
  if (blockIdx.x == 0 && t < 32) {
    z0[t] = 0u;
    z1[t] = 0u;
  }

  for (int i = t; i < nbuk; i += 256) lhist[i] = 0;
  __syncthreads();

  int e0 = blockIdx.x * TILE;
  int myd[16], mys[16], myrank[16];
#pragma unroll
  for (int j = 0; j < 16; ++j) {
    int e = e0 + t + j * 256;  // coalesced
    if (e < nE) {
      int d = dst[e];
      myd[j] = d;
      mys[j] = src[e];
      myrank[j] = atomicAdd(&lhist[d >> 7], 1);  // returns old -> local rank
      atomicAdd(&deg[d], 1);                     // global per-node degree
    } else {
      myd[j] = -1;
    }
  }
  __syncthreads();
  for (int i = t; i < nbuk; i += 256) {
    int c = lhist[i];
    gbase[i] = c ? atomicAdd(&bcur[((i << 3) | (int)xcc) * 16], c) : 0;
  }
  __syncthreads();
#pragma unroll
  for (int j = 0; j < 16; ++j) {
    if (myd[j] >= 0) {
      int b = myd[j] >> 7;
      int pos = gbase[b] + myrank[j];
      if (pos < SUBCAP) {
        int sub = (b << 3) | (int)xcc;
        ebuf[(size_t)sub * SUBCAP + pos] =
            ((uint32_t)(myd[j] & 127) << 20) | (uint32_t)mys[j];
      }
    }
  }
}

// Fused CSR-build + layer-1 GEMM (R21). Blocks [0,nbuk): prefix+fill using
// deg as the histogram (single ebuf pass). Blocks [nbuk, nbuk+gemmb): X@W1
// MFMA -> fp8 table, dn = rsqrt(deg+1) computed locally (deg ready from
// scatter; no dependence on build blocks).
__global__ __launch_bounds__(256) void build_gemm(const uint32_t* __restrict__ ebuf,
                                                  const int* __restrict__ bcur,
                                                  const int* __restrict__ deg,
                                                  float* __restrict__ dinv,
                                                  int* __restrict__ offs,
                                                  int* __restrict__ csr,
                                                  const float* __restrict__ X32,
                                                  const uint16_t* __restrict__ WTb,
                                                  uint8_t* __restrict__ tab,
                                                  int n, int nbuk) {
  __shared__ __align__(16) uint16_t sW[128 * 136];
  int t = threadIdx.x;

  if ((int)blockIdx.x >= nbuk) {
    // ---- GEMM path: 64 rows of X (fp32) @ W1 -> fp8 table ----
    int bid = (int)blockIdx.x - nbuk;
#pragma unroll
    for (int i = 0; i < 8; ++i) {
      int j = t + i * 256;
      int r = j >> 4, c = j & 15;
      float4 v = ((const float4*)WTb)[j];
      *(float4*)(sW + r * 136 + c * 8) = v;
    }
    __syncthreads();

    int wave = t >> 6, lane = t & 63;
    int quad = lane >> 4, l15 = lane & 15;
    int m = bid * 64 + wave * 16 + l15;
    int mm = min(m, n - 1);

    short8 a[4];
#pragma unroll
    for (int kc = 0; kc < 4; ++kc) {
      const float* p = X32 + (size_t)mm * 128 + kc * 32 + quad * 8;
      float4 lo = *(const float4*)p;
      float4 hi = *(const float4*)(p + 4);
      a[kc] = (short8){(short)f2bf(lo.x), (short)f2bf(lo.y),
                       (short)f2bf(lo.z), (short)f2bf(lo.w),
                       (short)f2bf(hi.x), (short)f2bf(hi.y),
                       (short)f2bf(hi.z), (short)f2bf(hi.w)};
    }

    f32x4 acc[8];
#pragma unroll
    for (int nn = 0; nn < 8; ++nn) acc[nn] = (f32x4){0.f, 0.f, 0.f, 0.f};

#pragma unroll
    for (int nn = 0; nn < 8; ++nn) {
      int nrow = nn * 16 + l15;
#pragma unroll
      for (int kc = 0; kc < 4; ++kc) {
        short8 b = *(const short8*)(sW + nrow * 136 + kc * 32 + quad * 8);
        acc[nn] = __builtin_amdgcn_mfma_f32_16x16x32_bf16(a[kc], b, acc[nn], 0, 0, 0);
      }
    }

    int mrow = bid * 64 + wave * 16 + quad * 4;
#pragma unroll
    for (int r = 0; r < 4; ++r) {
      int row = mrow + r;
      if (row < n) {
        float dn = rsqrtf((float)(deg[row] + 1));
#pragma unroll
        for (int nn = 0; nn < 8; ++nn) {
          tab[(size_t)row * 128 + nn * 16 + l15] = (uint8_t)f2e5m2(acc[nn][r] * dn);
        }
      }
    }
    return;
  }

  // ---- build path: hist = deg (no ebuf pass 1), prefix, fill, pads ----
  int b = (int)blockIdx.x;
  int base = b << 7;
  int* hist = (int*)sW;        // [128]
  int* pre  = (int*)sW + 128;  // [128]
  int* lcur = (int*)sW + 256;  // [128]

  if (t < 128) hist[t] = (base + t < n) ? deg[base + t] : 0;
  __syncthreads();
  if (t < 128) pre[t] = (hist[t] + 3) & ~3;  // ceil4 region sizes
  __syncthreads();
  for (int d = 1; d < 128; d <<= 1) {  // inclusive scan
    int v = (t >= d && t < 128) ? pre[t - d] : 0;
    __syncthreads();
    if (t < 128) pre[t] += v;
    __syncthreads();
  }
  if (t < 128) {
    int dg = hist[t];
    int start = b * CSRCAP + pre[t] - ((dg + 3) & ~3);  // 4-aligned
    lcur[t] = start;
    if (base + t < n) {
      dinv[base + t] = rsqrtf((float)(dg + 1));  // +1 self-loop
      offs[base + t] = start;
    }
  }
  __syncthreads();
#pragma unroll
  for (int x = 0; x < 8; ++x) {
    int sub = (b << 3) | x;
    int cnt = min(bcur[sub * 16], SUBCAP);
    const uint32_t* eb = ebuf + (size_t)sub * SUBCAP;
    for (int e = t; e < cnt; e += 256) {
      uint32_t ed = eb[e];
      int pos = atomicAdd(&lcur[ed >> 20], 1);
      csr[pos] = (int)((ed & 0xFFFFFu) << 7);  // byte offset into fp8 table
    }
  }
  // Pad slots [deg, ceil4(deg)) -> zero-row offset (row n). Disjoint from
  // fill writes, no barrier needed.
  if (t < 128) {
    int dg = hist[t];
    int c4 = (dg + 3) & ~3;
    int start = b * CSRCAP + pre[t] - c4;
    int zoff = n << 7;
    for (int p = dg; p < c4; ++p) csr[start + p] = zoff;
  }
}

// ---------------- fused gather (+ next-layer GEMM | + pool) ----------------

__device__ __forceinline__ void acc_pk(uint32_t u, h16x2& a01, h16x2& a23) {
  H2U p01, p23;
  p01.u = __builtin_amdgcn_perm(u, 0u, 0x05010400u);  // (b0<<8)|(b1<<24)
  p23.u = __builtin_amdgcn_perm(u, 0u, 0x07010600u);  // (b2<<8)|(b3<<24)
  a01 += p01.h;
  a23 += p23.h;
}

// 512 threads = 16 half-waves = 16 nodes/block. Phase 1: gather h rows into
// LDS sA (bf16); edge lists ceil4-padded with zero-row entries -> no scalar
// tail; 16 rows in flight (R21). Phase 2 (!POOL): 8 waves x 4 MFMA -> tabN =
// fp8(dinv*(h W)). Phase 2 (POOL): threads 0..127 mean-pool from LDS.
template <bool POOL>
__global__ __launch_bounds__(512) void gather_gemm(const uint8_t* __restrict__ tab,
                                                   const int* __restrict__ csr,
                                                   const int* __restrict__ offs,
                                                   const int* __restrict__ deg,
                                                   const float* __restrict__ dinv,
                                                   const float* __restrict__ b,
                                                   const uint16_t* __restrict__ WTb,
                                                   uint8_t* __restrict__ tabN,
                                                   const int* __restrict__ batch,
                                                   float* __restrict__ pool,
                                                   int n) {
  __shared__ uint16_t sW[POOL ? 8 : 128 * 136];  // B operand (W^T)
  __shared__ uint16_t sA[16 * 136];              // h rows, bf16, padded stride
  __shared__ int sb[16];                         // batch ids (POOL)
  int t = threadIdx.x;
  int blk = (int)blockIdx.x;

  if constexpr (!POOL) {
#pragma unroll
    for (int i = 0; i < 4; ++i) {
      int j = t + i * 512;  // 2048 float4 = 128x128 bf16
      int r = j >> 4, c = j & 15;
      float4 v = ((const float4*)WTb)[j];
      *(float4*)(sW + r * 136 + c * 8) = v;
    }
  } else {
    if (t < 16) sb[t] = batch[min(blk * 16 + t, n - 1)];
  }

  // ---- phase 1: gather (half-wave per node, tail-free, 16-deep) ----
  int hw = t >> 5;  // 0..15 = node slot
  int node = min(blk * 16 + hw, n - 1);
  int l = t & 31;
  int c = l * 4;  // feature/byte offset within row
  const uint8_t* tabc = tab + c;
  int e0 = offs[node];                     // 4-aligned by construction
  int e1 = e0 + ((deg[node] + 3) & ~3);    // ceil4: pads hit the zero row
  h16x2 a01 = (h16x2){(_Float16)0.f, (_Float16)0.f};
  h16x2 a23 = (h16x2){(_Float16)0.f, (_Float16)0.f};

  int e = e0;
  for (; e + 15 < e1; e += 16) {  // 16 rows in flight
    int4 c0 = *(const int4*)(csr + e);
    int4 c1 = *(const int4*)(csr + e + 4);
    int4 c2 = *(const int4*)(csr + e + 8);
    int4 c3 = *(const int4*)(csr + e + 12);
    uint32_t u[16];
    u[0]  = *(const uint32_t*)(tabc + c0.x);
    u[1]  = *(const uint32_t*)(tabc + c0.y);
    u[2]  = *(const uint32_t*)(tabc + c0.z);
    u[3]  = *(const uint32_t*)(tabc + c0.w);
    u[4]  = *(const uint32_t*)(tabc + c1.x);
    u[5]  = *(const uint32_t*)(tabc + c1.y);
    u[6]  = *(const uint32_t*)(tabc + c1.z);
    u[7]  = *(const uint32_t*)(tabc + c1.w);
    u[8]  = *(const uint32_t*)(tabc + c2.x);
    u[9]  = *(const uint32_t*)(tabc + c2.y);
    u[10] = *(const uint32_t*)(tabc + c2.z);
    u[11] = *(const uint32_t*)(tabc + c2.w);
    u[12] = *(const uint32_t*)(tabc + c3.x);
    u[13] = *(const uint32_t*)(tabc + c3.y);
    u[14] = *(const uint32_t*)(tabc + c3.z);
    u[15] = *(const uint32_t*)(tabc + c3.w);
#pragma unroll
    for (int j = 0; j < 16; ++j) acc_pk(u[j], a01, a23);
  }
  if (e + 7 < e1) {
    int4 ca = *(const int4*)(csr + e);
    int4 cb = *(const int4*)(csr + e + 4);
    uint32_t u[8];
    u[0] = *(const uint32_t*)(tabc + ca.x);
    u[1] = *(const uint32_t*)(tabc + ca.y);
    u[2] = *(const uint32_t*)(tabc + ca.z);
    u[3] = *(const uint32_t*)(tabc + ca.w);
    u[4] = *(const uint32_t*)(tabc + cb.x);
    u[5] = *(const uint32_t*)(tabc + cb.y);
    u[6] = *(const uint32_t*)(tabc + cb.z);
    u[7] = *(const uint32_t*)(tabc + cb.w);
#pragma unroll
    for (int j = 0; j < 8; ++j) acc_pk(u[j], a01, a23);
    e += 8;
  }
  if (e < e1) {  // one final 4-batch (remainder in {0,4})
    int4 ca = *(const int4*)(csr + e);
    uint32_t u[4];
    u[0] = *(const uint32_t*)(tabc + ca.x);
    u[1] = *(const uint32_t*)(tabc + ca.y);
    u[2] = *(const uint32_t*)(tabc + ca.z);
    u[3] = *(const uint32_t*)(tabc + ca.w);
#pragma unroll
    for (int j = 0; j < 4; ++j) acc_pk(u[j], a01, a23);
  }

  float a0 = (float)a01.x, a1 = (float)a01.y;
  float a2 = (float)a23.x, a3 = (float)a23.y;

  float dn = dinv[node];
  uint32_t uh = *(const uint32_t*)(tabc + node * 128);  // self-loop
  float4 bb = *(const float4*)(b + c);
  float o0 = (a0 + e5m2f(uh & 0xFFu)) * dn + bb.x;
  float o1 = (a1 + e5m2f((uh >> 8) & 0xFFu)) * dn + bb.y;
  float o2 = (a2 + e5m2f((uh >> 16) & 0xFFu)) * dn + bb.z;
  float o3 = (a3 + e5m2f(uh >> 24)) * dn + bb.w;
  o0 = o0 > 0.f ? o0 : expm1f(o0);
  o1 = o1 > 0.f ? o1 : expm1f(o1);
  o2 = o2 > 0.f ? o2 : expm1f(o2);
  o3 = o3 > 0.f ? o3 : expm1f(o3);
  uint2 po;
  po.x = f2bf(o0) | (f2bf(o1) << 16);
  po.y = f2bf(o2) | (f2bf(o3) << 16);
  *(uint2*)(sA + hw * 136 + c) = po;  // h row -> LDS (bf16)
  __syncthreads();

  if constexpr (POOL) {
    // ---- phase 2: sorted-batch mean-pool straight from LDS ----
    if (t < 128) {
      int base = blk * 16;
      int iend = min(16, n - base);
      float acc = 0.f;
      int cur = sb[0];
      for (int i = 0; i < iend; ++i) {
        int g = sb[i];
        if (g != cur) {
          atomicAdd(&pool[cur * 128 + t], acc);
          acc = 0.f;
          cur = g;
        }
        acc += bf2f((uint32_t)sA[i * 136 + t]);
      }
      atomicAdd(&pool[cur * 128 + t], acc);
    }
  } else {
    // ---- phase 2: 16x128 @ 128x128 MFMA, out -> fp8 table ----
    int wave = t >> 6, lane = t & 63;
    int quad = lane >> 4, l15 = lane & 15;
    f32x4 acc = (f32x4){0.f, 0.f, 0.f, 0.f};
#pragma unroll
    for (int kc = 0; kc < 4; ++kc) {
      short8 av = *(const short8*)(sA + l15 * 136 + kc * 32 + quad * 8);
      short8 bv = *(const short8*)(sW + (wave * 16 + l15) * 136 + kc * 32 + quad * 8);
      acc = __builtin_amdgcn_mfma_f32_16x16x32_bf16(av, bv, acc, 0, 0, 0);
    }
    int mrow = blk * 16 + quad * 4;
#pragma unroll
    for (int r = 0; r < 4; ++r) {
      int row = mrow + r;
      if (row < n) {
        float dno = dinv[row];
        tabN[(size_t)row * 128 + wave * 16 + l15] = (uint8_t)f2e5m2(acc[r] * dno);
      }
    }
  }
}

// ---------------- head ----------------

// One wave per graph: cnt (binary search), z_j = relu(g.Wc1_j + bc1_j),
// logit = shfl-reduce(z_j * Wc2_j) + bc2. Coalesced Wc1 reads (lane = j).
__global__ __launch_bounds__(64) void classifier_kernel(const float* __restrict__ pool,
                                                        const int* __restrict__ batch,
                                                        const float* __restrict__ Wc1,
                                                        const float* __restrict__ bc1,
                                                        const float* __restrict__ Wc2,
                                                        const float* __restrict__ bc2,
                                                        float* __restrict__ out, int n) {
  int g = blockIdx.x;   // graph id, 0..63
  int j = threadIdx.x;  // hidden unit, 0..63
  __shared__ float sg[128];

  // cnt for this graph (all lanes redundantly; 2 binary searches)
  int lo = 0, hi = n;
  while (lo < hi) {
    int mid = (lo + hi) >> 1;
    if (batch[mid] < g) lo = mid + 1; else hi = mid;
  }
  int a = lo;
  lo = 0; hi = n;
  while (lo < hi) {
    int mid = (lo + hi) >> 1;
    if (batch[mid] < g + 1) lo = mid + 1; else hi = mid;
  }
  float inv = 1.f / (float)max(lo - a, 1);

  sg[j] = pool[g * 128 + j] * inv;
  sg[j + 64] = pool[g * 128 + j + 64] * inv;
  __syncthreads();

  float acc = bc1[j];
#pragma unroll 4
  for (int k = 0; k < 128; ++k) acc += sg[k] * Wc1[k * 64 + j];  // coalesced in j
  float z = fmaxf(acc, 0.f);

  float v = z * Wc2[j];
#pragma unroll
  for (int m = 32; m > 0; m >>= 1) v += __shfl_xor(v, m, 64);
  if (j == 0) out[g] = 1.f / (1.f + expf(-(v + bc2[0])));
}

extern "C" void kernel_launch(void* const* d_in, const int* in_sizes, int n_in,
                              void* d_out, int out_size, void* d_ws, size_t ws_size,
                              hipStream_t stream) {
  const float* x   = (const float*)d_in[0];
  const int* ei    = (const int*)d_in[1];
  const int* batch = (const int*)d_in[2];
  const float* W1  = (const float*)d_in[3];
  const float* b1  = (const float*)d_in[4];
  const float* W2  = (const float*)d_in[5];
  const float* b2  = (const float*)d_in[6];
  const float* W3  = (const float*)d_in[7];
  const float* b3  = (const float*)d_in[8];
  const float* Wc1 = (const float*)d_in[9];
  const float* bc1 = (const float*)d_in[10];
  const float* Wc2 = (const float*)d_in[11];
  const float* bc2 = (const float*)d_in[12];

  int n  = in_sizes[2];
  int nE = in_sizes[1] / 2;
  const int* src = ei;
  const int* dst = ei + nE;
  int nbuk = (n + 127) >> 7;  // 128-node dst buckets

  // Workspace (~68 MB). Tables are (n+4) rows: row n is the shared zero row
  // used by csr pad entries. All segment element counts multiples of 4.
  size_t T = (size_t)(n + 4) * 128;  // table stride in bytes
  uint8_t*  tab0 = (uint8_t*)d_ws;                      // fp8 table A
  uint8_t*  tab1 = tab0 + T;                            // fp8 table B
  float* dinv    = (float*)(tab1 + T);
  int*   deg     = (int*)(dinv + n);
  int*   offs    = deg + n;                             // [n+4]
  int*   bcur    = offs + n + 4;                        // [nbuk*8*16] padded
  int*   csr     = bcur + nbuk * 8 * 16;                // [nbuk*CSRCAP]
  uint32_t* ebuf = (uint32_t*)(csr + (size_t)nbuk * CSRCAP);  // [nbuk*8*SUBCAP]
  uint16_t* WT   = (uint16_t*)(ebuf + (size_t)nbuk * 8 * SUBCAP);
  float* pool    = (float*)(WT + 3 * 16384);
  float* out     = (float*)d_out;

  hipMemsetAsync(bcur, 0, (size_t)nbuk * 8 * 16 * sizeof(int), stream);
  hipMemsetAsync(deg, 0, (size_t)n * sizeof(int), stream);
  bucket_scatter<<<(nE + TILE - 1) / TILE, 256, 0, stream>>>(
      src, dst, bcur, ebuf, deg, W1, W2, W3, WT, pool,
      (uint32_t*)(tab0 + (size_t)n * 128), (uint32_t*)(tab1 + (size_t)n * 128),
      nE, nbuk);

  int gemmb = (n + 63) / 64;
  build_gemm<<<nbuk + gemmb, 256, 0, stream>>>(ebuf, bcur, deg, dinv, offs, csr,
                                               x, WT, tab0, n, nbuk);

  int gfb = (n + 15) / 16;  // fused blocks: 16 nodes each
  gather_gemm<false><<<gfb, 512, 0, stream>>>(tab0, csr, offs, deg, dinv, b1,
                                              WT + 16384, tab1, nullptr, nullptr, n);
  gather_gemm<false><<<gfb, 512, 0, stream>>>(tab1, csr, offs, deg, dinv, b2,
                                              WT + 32768, tab0, nullptr, nullptr, n);
  gather_gemm<true><<<gfb, 512, 0, stream>>>(tab0, csr, offs, deg, dinv, b3,
                                             nullptr, nullptr, batch, pool, n);
  classifier_kernel<<<64, 64, 0, stream>>>(pool, batch, Wc1, bc1, Wc2, bc2, out, n);
}

// Round 9
// 320.607 us; speedup vs baseline: 1.1545x; 1.1545x over previous
//
#include <hip/hip_runtime.h>
#include <cstdint>
#include <cstddef>

// ---------------------------------------------------------------------------
// GCN: h = elu(D^-1/2 (A+I) D^-1/2 (h W) + b) x3, mean-pool, MLP head.
// R22: R20 baseline (320.3us, proven) + two unconfounded deltas:
//  (1) gather load batch 8 -> 16 rows in flight (R18/R21 both bundled this
//      with poison -- perm / global deg atomics; this time isolated).
//      Per-wave outstanding L3 reqs double; accumulation order unchanged.
//  (2) build hist pass: 4-way sub-banked LDS counters (1.6M atomics over
//      512 instead of 128 slots).
// R21 ledger: per-edge global atomicAdd(deg) = 86us scatter (66MB of
// write-allocate traffic, VALU 1.5%) -- never again. gather FETCH 84MB >>
// table 12.8MB => FETCH counts L2-miss-to-L3; gather is L3-latency-bound.
// ---------------------------------------------------------------------------

#define SUBCAP 512   // per-(bucket,XCD) capacity: mean 256, +16 sigma
#define CSRCAP 4608  // per-bucket csr region: 4096 max edges + ceil4 padding
#define TILE 4096    // edges per scatter block

typedef __attribute__((ext_vector_type(8))) short short8;   // 8 bf16 = 4 VGPRs
typedef __attribute__((ext_vector_type(4))) float f32x4;
typedef __attribute__((ext_vector_type(2))) _Float16 h16x2; // packed f16 pair

__device__ __forceinline__ float bf2f(uint32_t u) {
  return __uint_as_float(u << 16);
}
__device__ __forceinline__ uint32_t f2bf(float f) {  // round-to-nearest-even
  uint32_t x = __float_as_uint(f);
  return (x + 0x7FFFu + ((x >> 16) & 1u)) >> 16;
}

union H16 { _Float16 h; uint16_t u; };
union H2U { h16x2 h; uint32_t u; };

// f32 -> e5m2 byte (RNE via f16 then RNE-truncate mantissa to 2 bits)
__device__ __forceinline__ uint32_t f2e5m2(float f) {
  f = fminf(fmaxf(f, -30000.f), 30000.f);
  H16 cv;
  cv.h = (_Float16)f;
  uint32_t h = cv.u;
  uint32_t r = h + 0x7Fu + ((h >> 8) & 1u);
  return (r >> 8) & 0xFFu;
}

// e5m2 byte -> f32 (exact: e5m2 is truncated f16)
__device__ __forceinline__ float e5m2f(uint32_t b) {
  H16 cv;
  cv.u = (uint16_t)(b << 8);
  return (float)cv.h;
}

// ---------------- CSR build ----------------

// Block-aggregated, XCD-partitioned scatter. 4096 edges/block. (R10)
__global__ __launch_bounds__(256) void bucket_scatter(const int* __restrict__ src,
                                                      const int* __restrict__ dst,
                                                      int* __restrict__ bcur,
                                                      uint32_t* __restrict__ ebuf,
                                                      int nE, int nbuk) {
  uint32_t xcc;
  asm("s_getreg_b32 %0, hwreg(HW_REG_XCC_ID)" : "=s"(xcc));  // 0..7, wave-uniform
  __shared__ int lhist[1024];
  __shared__ int gbase[1024];
  int t = threadIdx.x;
  for (int i = t; i < nbuk; i += 256) lhist[i] = 0;
  __syncthreads();

  int e0 = blockIdx.x * TILE;
  int myd[16], mys[16], myrank[16];
#pragma unroll
  for (int j = 0; j < 16; ++j) {
    int e = e0 + t + j * 256;  // coalesced
    if (e < nE) {
      int d = dst[e];
      myd[j] = d;
      mys[j] = src[e];
      myrank[j] = atomicAdd(&lhist[d >> 7], 1);  // returns old -> local rank
    } else {
      myd[j] = -1;
    }
  }
  __syncthreads();
  for (int i = t; i < nbuk; i += 256) {
    int c = lhist[i];
    gbase[i] = c ? atomicAdd(&bcur[((i << 3) | (int)xcc) * 16], c) : 0;
  }
  __syncthreads();
#pragma unroll
  for (int j = 0; j < 16; ++j) {
    if (myd[j] >= 0) {
      int b = myd[j] >> 7;
      int pos = gbase[b] + myrank[j];
      if (pos < SUBCAP) {
        int sub = (b << 3) | (int)xcc;
        ebuf[(size_t)sub * SUBCAP + pos] =
            ((uint32_t)(myd[j] & 127) << 20) | (uint32_t)mys[j];
      }
    }
  }
}

// Fused hist + prefix + fill (R12) + side jobs: W cvt, pool zero, zero-row
// zero (R20). R22: hist pass uses 4-way sub-banked counters.
__global__ __launch_bounds__(256) void bucket_build(const uint32_t* __restrict__ ebuf,
                                                    const int* __restrict__ bcur,
                                                    int* __restrict__ deg,
                                                    float* __restrict__ dinv,
                                                    int* __restrict__ offs,
                                                    int* __restrict__ csr,
                                                    const float* __restrict__ W1,
                                                    const float* __restrict__ W2,
                                                    const float* __restrict__ W3,
                                                    uint16_t* __restrict__ WT,
                                                    float* __restrict__ pool,
                                                    uint32_t* __restrict__ z0,
                                                    uint32_t* __restrict__ z1,
                                                    int n, int nbuk) {
  int b = blockIdx.x;
  int base = b << 7;
  __shared__ int hist4[512];  // 4 sub-banks per node slot
  __shared__ int hist[128];
  __shared__ int pre[128];
  __shared__ int lcur[128];
  int t = threadIdx.x;

  // Side job 1: W1,W2,W3 fp32 [k][nn] -> WT bf16 [w][nn][k]  (grid-stride)
  for (int id = b * 256 + t; id < 3 * 16384; id += nbuk * 256) {
    int w = id >> 14;
    int rem = id & 16383;
    int k = rem >> 7, nn = rem & 127;
    const float* W = (w == 0) ? W1 : ((w == 1) ? W2 : W3);
    WT[w * 16384 + nn * 128 + k] = (uint16_t)f2bf(W[k * 128 + nn]);
  }
  // Side job 2: zero pool
  for (int id = b * 256 + t; id < 64 * 128; id += nbuk * 256) pool[id] = 0.f;
  // Side job 3: zero the zero rows of both fp8 tables (32 u32 each)
  for (int id = b * 256 + t; id < 32; id += nbuk * 256) {
    z0[id] = 0u;
    z1[id] = 0u;
  }

  if (t < 128) hist4[t] = 0;
  if (t < 128) hist4[t + 128] = 0;
  hist4[t + 256] = 0;  // covers 256..511 (t in [0,256))
  __syncthreads();
  int cnts[8];
#pragma unroll
  for (int x = 0; x < 8; ++x) {
    int sub = (b << 3) | x;
    int cnt = min(bcur[sub * 16], SUBCAP);
    cnts[x] = cnt;
    const uint32_t* eb = ebuf + (size_t)sub * SUBCAP;
    for (int e = t; e < cnt; e += 256)
      atomicAdd(&hist4[((eb[e] >> 20) << 2) | (t & 3)], 1);
  }
  __syncthreads();
  if (t < 128) {
    int dg = hist4[t * 4] + hist4[t * 4 + 1] + hist4[t * 4 + 2] + hist4[t * 4 + 3];
    hist[t] = dg;
    pre[t] = (dg + 3) & ~3;  // ceil4 region sizes
  }
  __syncthreads();
  for (int d = 1; d < 128; d <<= 1) {  // inclusive scan
    int v = (t >= d && t < 128) ? pre[t - d] : 0;
    __syncthreads();
    if (t < 128) pre[t] += v;
    __syncthreads();
  }
  if (t < 128) {
    int dg = hist[t];
    int start = b * CSRCAP + pre[t] - ((dg + 3) & ~3);  // 4-aligned
    lcur[t] = start;
    if (base + t < n) {
      deg[base + t] = dg;
      dinv[base + t] = rsqrtf((float)(dg + 1));  // +1 self-loop
      offs[base + t] = start;
    }
  }
  __syncthreads();
#pragma unroll
  for (int x = 0; x < 8; ++x) {
    int sub = (b << 3) | x;
    int cnt = cnts[x];
    const uint32_t* eb = ebuf + (size_t)sub * SUBCAP;
    for (int e = t; e < cnt; e += 256) {
      uint32_t ed = eb[e];
      int pos = atomicAdd(&lcur[ed >> 20], 1);
      csr[pos] = (int)((ed & 0xFFFFFu) << 7);  // byte offset into fp8 table
    }
  }
  __syncthreads();
  // Pad slots [deg, ceil4(deg)) -> zero-row offset (row n): gather runs
  // pure 4-aligned batches with no scalar tail.
  if (t < 128) {
    int dg = hist[t];
    int c4 = (dg + 3) & ~3;
    int start = b * CSRCAP + pre[t] - c4;
    int zoff = n << 7;
    for (int p = dg; p < c4; ++p) csr[start + p] = zoff;
  }
}

// ---------------- MFMA GEMM (layer 1 only): fp32 in, fp8(e5m2) table out ----

template <bool F32IN>
__global__ __launch_bounds__(256) void gemm_mfma(const uint16_t* __restrict__ Xb,
                                                 const float* __restrict__ X32,
                                                 const uint16_t* __restrict__ WTb,
                                                 const float* __restrict__ dinv,
                                                 uint8_t* __restrict__ tab, int n) {
  __shared__ uint16_t sW[128 * 136];
  int t = threadIdx.x;
#pragma unroll
  for (int i = 0; i < 8; ++i) {
    int j = t + i * 256;
    int r = j >> 4, c = j & 15;
    float4 v = ((const float4*)WTb)[j];
    *(float4*)(sW + r * 136 + c * 8) = v;
  }
  __syncthreads();

  int wave = t >> 6, lane = t & 63;
  int quad = lane >> 4, l15 = lane & 15;
  int m = blockIdx.x * 64 + wave * 16 + l15;
  int mm = min(m, n - 1);

  short8 a[4];
#pragma unroll
  for (int kc = 0; kc < 4; ++kc) {
    if constexpr (F32IN) {
      const float* p = X32 + (size_t)mm * 128 + kc * 32 + quad * 8;
      float4 lo = *(const float4*)p;
      float4 hi = *(const float4*)(p + 4);
      a[kc] = (short8){(short)f2bf(lo.x), (short)f2bf(lo.y),
                       (short)f2bf(lo.z), (short)f2bf(lo.w),
                       (short)f2bf(hi.x), (short)f2bf(hi.y),
                       (short)f2bf(hi.z), (short)f2bf(hi.w)};
    } else {
      a[kc] = *(const short8*)(Xb + (size_t)mm * 128 + kc * 32 + quad * 8);
    }
  }

  f32x4 acc[8];
#pragma unroll
  for (int nn = 0; nn < 8; ++nn) acc[nn] = (f32x4){0.f, 0.f, 0.f, 0.f};

#pragma unroll
  for (int nn = 0; nn < 8; ++nn) {
    int nrow = nn * 16 + l15;
#pragma unroll
    for (int kc = 0; kc < 4; ++kc) {
      short8 b = *(const short8*)(sW + nrow * 136 + kc * 32 + quad * 8);
      acc[nn] = __builtin_amdgcn_mfma_f32_16x16x32_bf16(a[kc], b, acc[nn], 0, 0, 0);
    }
  }

  int mrow = blockIdx.x * 64 + wave * 16 + quad * 4;
#pragma unroll
  for (int r = 0; r < 4; ++r) {
    int row = mrow + r;
    if (row < n) {
      float dn = dinv[row];
#pragma unroll
      for (int nn = 0; nn < 8; ++nn) {
        tab[(size_t)row * 128 + nn * 16 + l15] = (uint8_t)f2e5m2(acc[nn][r] * dn);
      }
    }
  }
}

// ---------------- fused gather (+ next-layer GEMM | + pool) ----------------

__device__ __forceinline__ void acc_pk(uint32_t u, h16x2& a01, h16x2& a23) {
  H2U p01, p23;
  p01.u = __builtin_amdgcn_perm(u, 0u, 0x05010400u);  // (b0<<8)|(b1<<24)
  p23.u = __builtin_amdgcn_perm(u, 0u, 0x07010600u);  // (b2<<8)|(b3<<24)
  a01 += p01.h;
  a23 += p23.h;
}

// 512 threads = 16 half-waves = 16 nodes/block. Phase 1: gather h rows into
// LDS sA (bf16); edge lists ceil4-padded with zero-row entries -> no scalar
// tail; 16 rows in flight (R22). Phase 2 (!POOL): 8 waves x 4 MFMA -> tabN =
// fp8(dinv*(h W)). Phase 2 (POOL): threads 0..127 mean-pool from LDS.
template <bool POOL>
__global__ __launch_bounds__(512) void gather_gemm(const uint8_t* __restrict__ tab,
                                                   const int* __restrict__ csr,
                                                   const int* __restrict__ offs,
                                                   const int* __restrict__ deg,
                                                   const float* __restrict__ dinv,
                                                   const float* __restrict__ b,
                                                   const uint16_t* __restrict__ WTb,
                                                   uint8_t* __restrict__ tabN,
                                                   const int* __restrict__ batch,
                                                   float* __restrict__ pool,
                                                   int n) {
  __shared__ uint16_t sW[POOL ? 8 : 128 * 136];  // B operand (W^T)
  __shared__ uint16_t sA[16 * 136];              // h rows, bf16, padded stride
  __shared__ int sb[16];                         // batch ids (POOL)
  int t = threadIdx.x;
  int blk = (int)blockIdx.x;

  if constexpr (!POOL) {
#pragma unroll
    for (int i = 0; i < 4; ++i) {
      int j = t + i * 512;  // 2048 float4 = 128x128 bf16
      int r = j >> 4, c = j & 15;
      float4 v = ((const float4*)WTb)[j];
      *(float4*)(sW + r * 136 + c * 8) = v;
    }
  } else {
    if (t < 16) sb[t] = batch[min(blk * 16 + t, n - 1)];
  }

  // ---- phase 1: gather (half-wave per node, tail-free, 16-deep) ----
  int hw = t >> 5;  // 0..15 = node slot
  int node = min(blk * 16 + hw, n - 1);
  int l = t & 31;
  int c = l * 4;  // feature/byte offset within row
  const uint8_t* tabc = tab + c;
  int e0 = offs[node];                     // 4-aligned by construction
  int e1 = e0 + ((deg[node] + 3) & ~3);    // ceil4: pads hit the zero row
  h16x2 a01 = (h16x2){(_Float16)0.f, (_Float16)0.f};
  h16x2 a23 = (h16x2){(_Float16)0.f, (_Float16)0.f};

  int e = e0;
  for (; e + 15 < e1; e += 16) {  // 16 rows in flight
    int4 c0 = *(const int4*)(csr + e);
    int4 c1 = *(const int4*)(csr + e + 4);
    int4 c2 = *(const int4*)(csr + e + 8);
    int4 c3 = *(const int4*)(csr + e + 12);
    uint32_t u[16];
    u[0]  = *(const uint32_t*)(tabc + c0.x);
    u[1]  = *(const uint32_t*)(tabc + c0.y);
    u[2]  = *(const uint32_t*)(tabc + c0.z);
    u[3]  = *(const uint32_t*)(tabc + c0.w);
    u[4]  = *(const uint32_t*)(tabc + c1.x);
    u[5]  = *(const uint32_t*)(tabc + c1.y);
    u[6]  = *(const uint32_t*)(tabc + c1.z);
    u[7]  = *(const uint32_t*)(tabc + c1.w);
    u[8]  = *(const uint32_t*)(tabc + c2.x);
    u[9]  = *(const uint32_t*)(tabc + c2.y);
    u[10] = *(const uint32_t*)(tabc + c2.z);
    u[11] = *(const uint32_t*)(tabc + c2.w);
    u[12] = *(const uint32_t*)(tabc + c3.x);
    u[13] = *(const uint32_t*)(tabc + c3.y);
    u[14] = *(const uint32_t*)(tabc + c3.z);
    u[15] = *(const uint32_t*)(tabc + c3.w);
#pragma unroll
    for (int j = 0; j < 16; ++j) acc_pk(u[j], a01, a23);
  }
  if (e + 7 < e1) {
    int4 ca = *(const int4*)(csr + e);
    int4 cb = *(const int4*)(csr + e + 4);
    uint32_t u[8];
    u[0] = *(const uint32_t*)(tabc + ca.x);
    u[1] = *(const uint32_t*)(tabc + ca.y);
    u[2] = *(const uint32_t*)(tabc + ca.z);
    u[3] = *(const uint32_t*)(tabc + ca.w);
    u[4] = *(const uint32_t*)(tabc + cb.x);
    u[5] = *(const uint32_t*)(tabc + cb.y);
    u[6] = *(const uint32_t*)(tabc + cb.z);
    u[7] = *(const uint32_t*)(tabc + cb.w);
#pragma unroll
    for (int j = 0; j < 8; ++j) acc_pk(u[j], a01, a23);
    e += 8;
  }
  if (e < e1) {  // one final 4-batch (remainder in {0,4})
    int4 ca = *(const int4*)(csr + e);
    uint32_t u[4];
    u[0] = *(const uint32_t*)(tabc + ca.x);
    u[1] = *(const uint32_t*)(tabc + ca.y);
    u[2] = *(const uint32_t*)(tabc + ca.z);
    u[3] = *(const uint32_t*)(tabc + ca.w);
#pragma unroll
    for (int j = 0; j < 4; ++j) acc_pk(u[j], a01, a23);
  }

  float a0 = (float)a01.x, a1 = (float)a01.y;
  float a2 = (float)a23.x, a3 = (float)a23.y;

  float dn = dinv[node];
  uint32_t uh = *(const uint32_t*)(tabc + node * 128);  // self-loop
  float4 bb = *(const float4*)(b + c);
  float o0 = (a0 + e5m2f(uh & 0xFFu)) * dn + bb.x;
  float o1 = (a1 + e5m2f((uh >> 8) & 0xFFu)) * dn + bb.y;
  float o2 = (a2 + e5m2f((uh >> 16) & 0xFFu)) * dn + bb.z;
  float o3 = (a3 + e5m2f(uh >> 24)) * dn + bb.w;
  o0 = o0 > 0.f ? o0 : expm1f(o0);
  o1 = o1 > 0.f ? o1 : expm1f(o1);
  o2 = o2 > 0.f ? o2 : expm1f(o2);
  o3 = o3 > 0.f ? o3 : expm1f(o3);
  uint2 po;
  po.x = f2bf(o0) | (f2bf(o1) << 16);
  po.y = f2bf(o2) | (f2bf(o3) << 16);
  *(uint2*)(sA + hw * 136 + c) = po;  // h row -> LDS (bf16)
  __syncthreads();

  if constexpr (POOL) {
    // ---- phase 2: sorted-batch mean-pool straight from LDS ----
    if (t < 128) {
      int base = blk * 16;
      int iend = min(16, n - base);
      float acc = 0.f;
      int cur = sb[0];
      for (int i = 0; i < iend; ++i) {
        int g = sb[i];
        if (g != cur) {
          atomicAdd(&pool[cur * 128 + t], acc);
          acc = 0.f;
          cur = g;
        }
        acc += bf2f((uint32_t)sA[i * 136 + t]);
      }
      atomicAdd(&pool[cur * 128 + t], acc);
    }
  } else {
    // ---- phase 2: 16x128 @ 128x128 MFMA, out -> fp8 table ----
    int wave = t >> 6, lane = t & 63;
    int quad = lane >> 4, l15 = lane & 15;
    f32x4 acc = (f32x4){0.f, 0.f, 0.f, 0.f};
#pragma unroll
    for (int kc = 0; kc < 4; ++kc) {
      short8 av = *(const short8*)(sA + l15 * 136 + kc * 32 + quad * 8);
      short8 bv = *(const short8*)(sW + (wave * 16 + l15) * 136 + kc * 32 + quad * 8);
      acc = __builtin_amdgcn_mfma_f32_16x16x32_bf16(av, bv, acc, 0, 0, 0);
    }
    int mrow = blk * 16 + quad * 4;
#pragma unroll
    for (int r = 0; r < 4; ++r) {
      int row = mrow + r;
      if (row < n) {
        float dno = dinv[row];
        tabN[(size_t)row * 128 + wave * 16 + l15] = (uint8_t)f2e5m2(acc[r] * dno);
      }
    }
  }
}

// ---------------- head ----------------

// One wave per graph: cnt (binary search), z_j = relu(g.Wc1_j + bc1_j),
// logit = shfl-reduce(z_j * Wc2_j) + bc2. Coalesced Wc1 reads (lane = j).
__global__ __launch_bounds__(64) void classifier_kernel(const float* __restrict__ pool,
                                                        const int* __restrict__ batch,
                                                        const float* __restrict__ Wc1,
                                                        const float* __restrict__ bc1,
                                                        const float* __restrict__ Wc2,
                                                        const float* __restrict__ bc2,
                                                        float* __restrict__ out, int n) {
  int g = blockIdx.x;   // graph id, 0..63
  int j = threadIdx.x;  // hidden unit, 0..63
  __shared__ float sg[128];

  // cnt for this graph (all lanes redundantly; 2 binary searches)
  int lo = 0, hi = n;
  while (lo < hi) {
    int mid = (lo + hi) >> 1;
    if (batch[mid] < g) lo = mid + 1; else hi = mid;
  }
  int a = lo;
  lo = 0; hi = n;
  while (lo < hi) {
    int mid = (lo + hi) >> 1;
    if (batch[mid] < g + 1) lo = mid + 1; else hi = mid;
  }
  float inv = 1.f / (float)max(lo - a, 1);

  sg[j] = pool[g * 128 + j] * inv;
  sg[j + 64] = pool[g * 128 + j + 64] * inv;
  __syncthreads();

  float acc = bc1[j];
#pragma unroll 4
  for (int k = 0; k < 128; ++k) acc += sg[k] * Wc1[k * 64 + j];  // coalesced in j
  float z = fmaxf(acc, 0.f);

  float v = z * Wc2[j];
#pragma unroll
  for (int m = 32; m > 0; m >>= 1) v += __shfl_xor(v, m, 64);
  if (j == 0) out[g] = 1.f / (1.f + expf(-(v + bc2[0])));
}

extern "C" void kernel_launch(void* const* d_in, const int* in_sizes, int n_in,
                              void* d_out, int out_size, void* d_ws, size_t ws_size,
                              hipStream_t stream) {
  const float* x   = (const float*)d_in[0];
  const int* ei    = (const int*)d_in[1];
  const int* batch = (const int*)d_in[2];
  const float* W1  = (const float*)d_in[3];
  const float* b1  = (const float*)d_in[4];
  const float* W2  = (const float*)d_in[5];
  const float* b2  = (const float*)d_in[6];
  const float* W3  = (const float*)d_in[7];
  const float* b3  = (const float*)d_in[8];
  const float* Wc1 = (const float*)d_in[9];
  const float* bc1 = (const float*)d_in[10];
  const float* Wc2 = (const float*)d_in[11];
  const float* bc2 = (const float*)d_in[12];

  int n  = in_sizes[2];
  int nE = in_sizes[1] / 2;
  const int* src = ei;
  const int* dst = ei + nE;
  int nbuk = (n + 127) >> 7;  // 128-node dst buckets

  // Workspace (~68 MB). Tables are (n+4) rows: row n is the shared zero row
  // used by csr pad entries. All segment element counts multiples of 4.
  size_t T = (size_t)(n + 4) * 128;  // table stride in bytes
  uint8_t*  tab0 = (uint8_t*)d_ws;                      // fp8 table A
  uint8_t*  tab1 = tab0 + T;                            // fp8 table B
  float* dinv    = (float*)(tab1 + T);
  int*   deg     = (int*)(dinv + n);
  int*   offs    = deg + n;                             // [n+4]
  int*   bcur    = offs + n + 4;                        // [nbuk*8*16] padded
  int*   csr     = bcur + nbuk * 8 * 16;                // [nbuk*CSRCAP]
  uint32_t* ebuf = (uint32_t*)(csr + (size_t)nbuk * CSRCAP);  // [nbuk*8*SUBCAP]
  uint16_t* WT   = (uint16_t*)(ebuf + (size_t)nbuk * 8 * SUBCAP);
  float* pool    = (float*)(WT + 3 * 16384);
  float* out     = (float*)d_out;

  hipMemsetAsync(bcur, 0, (size_t)nbuk * 8 * 16 * sizeof(int), stream);
  bucket_scatter<<<(nE + TILE - 1) / TILE, 256, 0, stream>>>(src, dst, bcur, ebuf, nE, nbuk);
  bucket_build<<<nbuk, 256, 0, stream>>>(ebuf, bcur, deg, dinv, offs, csr,
                                         W1, W2, W3, WT, pool,
                                         (uint32_t*)(tab0 + (size_t)n * 128),
                                         (uint32_t*)(tab1 + (size_t)n * 128),
                                         n, nbuk);

  int gfb = (n + 15) / 16;  // fused blocks: 16 nodes each
  gemm_mfma<true><<<(n + 63) / 64, 256, 0, stream>>>(nullptr, x, WT, dinv, tab0, n);
  gather_gemm<false><<<gfb, 512, 0, stream>>>(tab0, csr, offs, deg, dinv, b1,
                                              WT + 16384, tab1, nullptr, nullptr, n);
  gather_gemm<false><<<gfb, 512, 0, stream>>>(tab1, csr, offs, deg, dinv, b2,
                                              WT + 32768, tab0, nullptr, nullptr, n);
  gather_gemm<true><<<gfb, 512, 0, stream>>>(tab0, csr, offs, deg, dinv, b3,
                                             nullptr, nullptr, batch, pool, n);
  classifier_kernel<<<64, 64, 0, stream>>>(pool, batch, Wc1, bc1, Wc2, bc2, out, n);
}

// Round 10
// 317.905 us; speedup vs baseline: 1.1643x; 1.0085x over previous
//
#include <hip/hip_runtime.h>
#include <cstdint>
#include <cstddef>

// ---------------------------------------------------------------------------
// GCN: h = elu(D^-1/2 (A+I) D^-1/2 (h W) + b) x3, mean-pool, MLP head.
// R23: fixed-stride CSR (64 slots/node). Build's hist pass + 128-scan existed
// only to compact per-node segments; with a fixed 64-entry region per node
// (P(deg>=64) ~ 1e-21 at Poisson(16), write-guarded) build collapses to ONE
// ebuf pass: pos = atomicAdd(lcur[node]) from base node*64, then deg/dinv/
// pads. Deletes a 6.4MB ebuf read, 1.6M LDS atomics, ~16 barriers. Gather
// drops the offs[] load (e0 = node<<6). Everything else == R20/R22 (320.3).
// Ledger: R22 16-deep batch = neutral (VGPR 20->32 cut occupancy exactly as
// much as MLP gained; gather is at its ~51us floor for this structure).
// ---------------------------------------------------------------------------

#define SUBCAP 512   // per-(bucket,XCD) capacity: mean 256, +16 sigma
#define NSLOT 64     // fixed csr slots per node (max deg guard)
#define TILE 4096    // edges per scatter block

typedef __attribute__((ext_vector_type(8))) short short8;   // 8 bf16 = 4 VGPRs
typedef __attribute__((ext_vector_type(4))) float f32x4;
typedef __attribute__((ext_vector_type(2))) _Float16 h16x2; // packed f16 pair

__device__ __forceinline__ float bf2f(uint32_t u) {
  return __uint_as_float(u << 16);
}
__device__ __forceinline__ uint32_t f2bf(float f) {  // round-to-nearest-even
  uint32_t x = __float_as_uint(f);
  return (x + 0x7FFFu + ((x >> 16) & 1u)) >> 16;
}

union H16 { _Float16 h; uint16_t u; };
union H2U { h16x2 h; uint32_t u; };

// f32 -> e5m2 byte (RNE via f16 then RNE-truncate mantissa to 2 bits)
__device__ __forceinline__ uint32_t f2e5m2(float f) {
  f = fminf(fmaxf(f, -30000.f), 30000.f);
  H16 cv;
  cv.h = (_Float16)f;
  uint32_t h = cv.u;
  uint32_t r = h + 0x7Fu + ((h >> 8) & 1u);
  return (r >> 8) & 0xFFu;
}

// e5m2 byte -> f32 (exact: e5m2 is truncated f16)
__device__ __forceinline__ float e5m2f(uint32_t b) {
  H16 cv;
  cv.u = (uint16_t)(b << 8);
  return (float)cv.h;
}

// ---------------- CSR build ----------------

// Block-aggregated, XCD-partitioned scatter. 4096 edges/block. (R10)
__global__ __launch_bounds__(256) void bucket_scatter(const int* __restrict__ src,
                                                      const int* __restrict__ dst,
                                                      int* __restrict__ bcur,
                                                      uint32_t* __restrict__ ebuf,
                                                      int nE, int nbuk) {
  uint32_t xcc;
  asm("s_getreg_b32 %0, hwreg(HW_REG_XCC_ID)" : "=s"(xcc));  // 0..7, wave-uniform
  __shared__ int lhist[1024];
  __shared__ int gbase[1024];
  int t = threadIdx.x;
  for (int i = t; i < nbuk; i += 256) lhist[i] = 0;
  __syncthreads();

  int e0 = blockIdx.x * TILE;
  int myd[16], mys[16], myrank[16];
#pragma unroll
  for (int j = 0; j < 16; ++j) {
    int e = e0 + t + j * 256;  // coalesced
    if (e < nE) {
      int d = dst[e];
      myd[j] = d;
      mys[j] = src[e];
      myrank[j] = atomicAdd(&lhist[d >> 7], 1);  // returns old -> local rank
    } else {
      myd[j] = -1;
    }
  }
  __syncthreads();
  for (int i = t; i < nbuk; i += 256) {
    int c = lhist[i];
    gbase[i] = c ? atomicAdd(&bcur[((i << 3) | (int)xcc) * 16], c) : 0;
  }
  __syncthreads();
#pragma unroll
  for (int j = 0; j < 16; ++j) {
    if (myd[j] >= 0) {
      int b = myd[j] >> 7;
      int pos = gbase[b] + myrank[j];
      if (pos < SUBCAP) {
        int sub = (b << 3) | (int)xcc;
        ebuf[(size_t)sub * SUBCAP + pos] =
            ((uint32_t)(myd[j] & 127) << 20) | (uint32_t)mys[j];
      }
    }
  }
}

// Fixed-stride CSR fill (R23): single ebuf pass, pos = atomicAdd from base
// node*NSLOT; then deg/dinv/pads. Side jobs: W cvt, pool zero, zero rows.
__global__ __launch_bounds__(256) void bucket_build(const uint32_t* __restrict__ ebuf,
                                                    const int* __restrict__ bcur,
                                                    int* __restrict__ deg,
                                                    float* __restrict__ dinv,
                                                    int* __restrict__ csr,
                                                    const float* __restrict__ W1,
                                                    const float* __restrict__ W2,
                                                    const float* __restrict__ W3,
                                                    uint16_t* __restrict__ WT,
                                                    float* __restrict__ pool,
                                                    uint32_t* __restrict__ z0,
                                                    uint32_t* __restrict__ z1,
                                                    int n, int nbuk) {
  int b = blockIdx.x;
  int base = b << 7;
  __shared__ int lcur[128];
  int t = threadIdx.x;

  // Side job 1: W1,W2,W3 fp32 [k][nn] -> WT bf16 [w][nn][k]  (grid-stride)
  for (int id = b * 256 + t; id < 3 * 16384; id += nbuk * 256) {
    int w = id >> 14;
    int rem = id & 16383;
    int k = rem >> 7, nn = rem & 127;
    const float* W = (w == 0) ? W1 : ((w == 1) ? W2 : W3);
    WT[w * 16384 + nn * 128 + k] = (uint16_t)f2bf(W[k * 128 + nn]);
  }
  // Side job 2: zero pool
  for (int id = b * 256 + t; id < 64 * 128; id += nbuk * 256) pool[id] = 0.f;
  // Side job 3: zero the zero rows of both fp8 tables (32 u32 each)
  for (int id = b * 256 + t; id < 32; id += nbuk * 256) {
    z0[id] = 0u;
    z1[id] = 0u;
  }

  if (t < 128) lcur[t] = (base + t) * NSLOT;
  __syncthreads();

  // Single fill pass over the bucket's 8 XCD sub-buffers.
#pragma unroll
  for (int x = 0; x < 8; ++x) {
    int sub = (b << 3) | x;
    int cnt = min(bcur[sub * 16], SUBCAP);
    const uint32_t* eb = ebuf + (size_t)sub * SUBCAP;
    for (int e = t; e < cnt; e += 256) {
      uint32_t ed = eb[e];
      int nd = ed >> 20;
      int start = (base + nd) * NSLOT;
      int pos = atomicAdd(&lcur[nd], 1);
      if (pos < start + NSLOT)
        csr[pos] = (int)((ed & 0xFFFFFu) << 7);  // byte offset into fp8 table
    }
  }
  __syncthreads();
  // deg/dinv + pad slots [deg, ceil4(deg)) -> zero-row offset (row n).
  if (t < 128 && base + t < n) {
    int start = (base + t) * NSLOT;
    int dg = min(lcur[t] - start, NSLOT);
    deg[base + t] = dg;
    dinv[base + t] = rsqrtf((float)(dg + 1));  // +1 self-loop
    int c4 = (dg + 3) & ~3;
    int zoff = n << 7;
    for (int p = dg; p < c4; ++p) csr[start + p] = zoff;
  }
}

// ---------------- MFMA GEMM (layer 1 only): fp32 in, fp8(e5m2) table out ----

template <bool F32IN>
__global__ __launch_bounds__(256) void gemm_mfma(const uint16_t* __restrict__ Xb,
                                                 const float* __restrict__ X32,
                                                 const uint16_t* __restrict__ WTb,
                                                 const float* __restrict__ dinv,
                                                 uint8_t* __restrict__ tab, int n) {
  __shared__ uint16_t sW[128 * 136];
  int t = threadIdx.x;
#pragma unroll
  for (int i = 0; i < 8; ++i) {
    int j = t + i * 256;
    int r = j >> 4, c = j & 15;
    float4 v = ((const float4*)WTb)[j];
    *(float4*)(sW + r * 136 + c * 8) = v;
  }
  __syncthreads();

  int wave = t >> 6, lane = t & 63;
  int quad = lane >> 4, l15 = lane & 15;
  int m = blockIdx.x * 64 + wave * 16 + l15;
  int mm = min(m, n - 1);

  short8 a[4];
#pragma unroll
  for (int kc = 0; kc < 4; ++kc) {
    if constexpr (F32IN) {
      const float* p = X32 + (size_t)mm * 128 + kc * 32 + quad * 8;
      float4 lo = *(const float4*)p;
      float4 hi = *(const float4*)(p + 4);
      a[kc] = (short8){(short)f2bf(lo.x), (short)f2bf(lo.y),
                       (short)f2bf(lo.z), (short)f2bf(lo.w),
                       (short)f2bf(hi.x), (short)f2bf(hi.y),
                       (short)f2bf(hi.z), (short)f2bf(hi.w)};
    } else {
      a[kc] = *(const short8*)(Xb + (size_t)mm * 128 + kc * 32 + quad * 8);
    }
  }

  f32x4 acc[8];
#pragma unroll
  for (int nn = 0; nn < 8; ++nn) acc[nn] = (f32x4){0.f, 0.f, 0.f, 0.f};

#pragma unroll
  for (int nn = 0; nn < 8; ++nn) {
    int nrow = nn * 16 + l15;
#pragma unroll
    for (int kc = 0; kc < 4; ++kc) {
      short8 b = *(const short8*)(sW + nrow * 136 + kc * 32 + quad * 8);
      acc[nn] = __builtin_amdgcn_mfma_f32_16x16x32_bf16(a[kc], b, acc[nn], 0, 0, 0);
    }
  }

  int mrow = blockIdx.x * 64 + wave * 16 + quad * 4;
#pragma unroll
  for (int r = 0; r < 4; ++r) {
    int row = mrow + r;
    if (row < n) {
      float dn = dinv[row];
#pragma unroll
      for (int nn = 0; nn < 8; ++nn) {
        tab[(size_t)row * 128 + nn * 16 + l15] = (uint8_t)f2e5m2(acc[nn][r] * dn);
      }
    }
  }
}

// ---------------- fused gather (+ next-layer GEMM | + pool) ----------------

__device__ __forceinline__ void acc_pk(uint32_t u, h16x2& a01, h16x2& a23) {
  H2U p01, p23;
  p01.u = __builtin_amdgcn_perm(u, 0u, 0x05010400u);  // (b0<<8)|(b1<<24)
  p23.u = __builtin_amdgcn_perm(u, 0u, 0x07010600u);  // (b2<<8)|(b3<<24)
  a01 += p01.h;
  a23 += p23.h;
}

// 512 threads = 16 half-waves = 16 nodes/block. Phase 1: gather h rows into
// LDS sA (bf16); fixed-stride csr (e0 = node*NSLOT, no offs load), edge lists
// ceil4-padded with zero-row entries -> no scalar tail. Phase 2 (!POOL): 8
// waves x 4 MFMA -> tabN = fp8(dinv*(h W)). Phase 2 (POOL): mean-pool.
template <bool POOL>
__global__ __launch_bounds__(512) void gather_gemm(const uint8_t* __restrict__ tab,
                                                   const int* __restrict__ csr,
                                                   const int* __restrict__ deg,
                                                   const float* __restrict__ dinv,
                                                   const float* __restrict__ b,
                                                   const uint16_t* __restrict__ WTb,
                                                   uint8_t* __restrict__ tabN,
                                                   const int* __restrict__ batch,
                                                   float* __restrict__ pool,
                                                   int n) {
  __shared__ uint16_t sW[POOL ? 8 : 128 * 136];  // B operand (W^T)
  __shared__ uint16_t sA[16 * 136];              // h rows, bf16, padded stride
  __shared__ int sb[16];                         // batch ids (POOL)
  int t = threadIdx.x;
  int blk = (int)blockIdx.x;

  if constexpr (!POOL) {
#pragma unroll
    for (int i = 0; i < 4; ++i) {
      int j = t + i * 512;  // 2048 float4 = 128x128 bf16
      int r = j >> 4, c = j & 15;
      float4 v = ((const float4*)WTb)[j];
      *(float4*)(sW + r * 136 + c * 8) = v;
    }
  } else {
    if (t < 16) sb[t] = batch[min(blk * 16 + t, n - 1)];
  }

  // ---- phase 1: gather (half-wave per node, tail-free 4-aligned loop) ----
  int hw = t >> 5;  // 0..15 = node slot
  int node = min(blk * 16 + hw, n - 1);
  int l = t & 31;
  int c = l * 4;  // feature/byte offset within row
  const uint8_t* tabc = tab + c;
  int e0 = node * NSLOT;                   // fixed-stride csr
  int e1 = e0 + ((deg[node] + 3) & ~3);    // ceil4: pads hit the zero row
  h16x2 a01 = (h16x2){(_Float16)0.f, (_Float16)0.f};
  h16x2 a23 = (h16x2){(_Float16)0.f, (_Float16)0.f};

  int e = e0;
  for (; e + 7 < e1; e += 8) {
    int4 ca = *(const int4*)(csr + e);
    int4 cb = *(const int4*)(csr + e + 4);
    uint32_t u[8];
    u[0] = *(const uint32_t*)(tabc + ca.x);
    u[1] = *(const uint32_t*)(tabc + ca.y);
    u[2] = *(const uint32_t*)(tabc + ca.z);
    u[3] = *(const uint32_t*)(tabc + ca.w);
    u[4] = *(const uint32_t*)(tabc + cb.x);
    u[5] = *(const uint32_t*)(tabc + cb.y);
    u[6] = *(const uint32_t*)(tabc + cb.z);
    u[7] = *(const uint32_t*)(tabc + cb.w);
#pragma unroll
    for (int j = 0; j < 8; ++j) acc_pk(u[j], a01, a23);
  }
  if (e < e1) {  // exactly one 4-batch possible (ceil4 % 8 ∈ {0,4})
    int4 ca = *(const int4*)(csr + e);
    uint32_t u[4];
    u[0] = *(const uint32_t*)(tabc + ca.x);
    u[1] = *(const uint32_t*)(tabc + ca.y);
    u[2] = *(const uint32_t*)(tabc + ca.z);
    u[3] = *(const uint32_t*)(tabc + ca.w);
#pragma unroll
    for (int j = 0; j < 4; ++j) acc_pk(u[j], a01, a23);
  }

  float a0 = (float)a01.x, a1 = (float)a01.y;
  float a2 = (float)a23.x, a3 = (float)a23.y;

  float dn = dinv[node];
  uint32_t uh = *(const uint32_t*)(tabc + node * 128);  // self-loop
  float4 bb = *(const float4*)(b + c);
  float o0 = (a0 + e5m2f(uh & 0xFFu)) * dn + bb.x;
  float o1 = (a1 + e5m2f((uh >> 8) & 0xFFu)) * dn + bb.y;
  float o2 = (a2 + e5m2f((uh >> 16) & 0xFFu)) * dn + bb.z;
  float o3 = (a3 + e5m2f(uh >> 24)) * dn + bb.w;
  o0 = o0 > 0.f ? o0 : expm1f(o0);
  o1 = o1 > 0.f ? o1 : expm1f(o1);
  o2 = o2 > 0.f ? o2 : expm1f(o2);
  o3 = o3 > 0.f ? o3 : expm1f(o3);
  uint2 po;
  po.x = f2bf(o0) | (f2bf(o1) << 16);
  po.y = f2bf(o2) | (f2bf(o3) << 16);
  *(uint2*)(sA + hw * 136 + c) = po;  // h row -> LDS (bf16)
  __syncthreads();

  if constexpr (POOL) {
    // ---- phase 2: sorted-batch mean-pool straight from LDS ----
    if (t < 128) {
      int base = blk * 16;
      int iend = min(16, n - base);
      float acc = 0.f;
      int cur = sb[0];
      for (int i = 0; i < iend; ++i) {
        int g = sb[i];
        if (g != cur) {
          atomicAdd(&pool[cur * 128 + t], acc);
          acc = 0.f;
          cur = g;
        }
        acc += bf2f((uint32_t)sA[i * 136 + t]);
      }
      atomicAdd(&pool[cur * 128 + t], acc);
    }
  } else {
    // ---- phase 2: 16x128 @ 128x128 MFMA, out -> fp8 table ----
    int wave = t >> 6, lane = t & 63;
    int quad = lane >> 4, l15 = lane & 15;
    f32x4 acc = (f32x4){0.f, 0.f, 0.f, 0.f};
#pragma unroll
    for (int kc = 0; kc < 4; ++kc) {
      short8 av = *(const short8*)(sA + l15 * 136 + kc * 32 + quad * 8);
      short8 bv = *(const short8*)(sW + (wave * 16 + l15) * 136 + kc * 32 + quad * 8);
      acc = __builtin_amdgcn_mfma_f32_16x16x32_bf16(av, bv, acc, 0, 0, 0);
    }
    int mrow = blk * 16 + quad * 4;
#pragma unroll
    for (int r = 0; r < 4; ++r) {
      int row = mrow + r;
      if (row < n) {
        float dno = dinv[row];
        tabN[(size_t)row * 128 + wave * 16 + l15] = (uint8_t)f2e5m2(acc[r] * dno);
      }
    }
  }
}

// ---------------- head ----------------

// One wave per graph: cnt (binary search), z_j = relu(g.Wc1_j + bc1_j),
// logit = shfl-reduce(z_j * Wc2_j) + bc2. Coalesced Wc1 reads (lane = j).
__global__ __launch_bounds__(64) void classifier_kernel(const float* __restrict__ pool,
                                                        const int* __restrict__ batch,
                                                        const float* __restrict__ Wc1,
                                                        const float* __restrict__ bc1,
                                                        const float* __restrict__ Wc2,
                                                        const float* __restrict__ bc2,
                                                        float* __restrict__ out, int n) {
  int g = blockIdx.x;   // graph id, 0..63
  int j = threadIdx.x;  // hidden unit, 0..63
  __shared__ float sg[128];

  // cnt for this graph (all lanes redundantly; 2 binary searches)
  int lo = 0, hi = n;
  while (lo < hi) {
    int mid = (lo + hi) >> 1;
    if (batch[mid] < g) lo = mid + 1; else hi = mid;
  }
  int a = lo;
  lo = 0; hi = n;
  while (lo < hi) {
    int mid = (lo + hi) >> 1;
    if (batch[mid] < g + 1) lo = mid + 1; else hi = mid;
  }
  float inv = 1.f / (float)max(lo - a, 1);

  sg[j] = pool[g * 128 + j] * inv;
  sg[j + 64] = pool[g * 128 + j + 64] * inv;
  __syncthreads();

  float acc = bc1[j];
#pragma unroll 4
  for (int k = 0; k < 128; ++k) acc += sg[k] * Wc1[k * 64 + j];  // coalesced in j
  float z = fmaxf(acc, 0.f);

  float v = z * Wc2[j];
#pragma unroll
  for (int m = 32; m > 0; m >>= 1) v += __shfl_xor(v, m, 64);
  if (j == 0) out[g] = 1.f / (1.f + expf(-(v + bc2[0])));
}

extern "C" void kernel_launch(void* const* d_in, const int* in_sizes, int n_in,
                              void* d_out, int out_size, void* d_ws, size_t ws_size,
                              hipStream_t stream) {
  const float* x   = (const float*)d_in[0];
  const int* ei    = (const int*)d_in[1];
  const int* batch = (const int*)d_in[2];
  const float* W1  = (const float*)d_in[3];
  const float* b1  = (const float*)d_in[4];
  const float* W2  = (const float*)d_in[5];
  const float* b2  = (const float*)d_in[6];
  const float* W3  = (const float*)d_in[7];
  const float* b3  = (const float*)d_in[8];
  const float* Wc1 = (const float*)d_in[9];
  const float* bc1 = (const float*)d_in[10];
  const float* Wc2 = (const float*)d_in[11];
  const float* bc2 = (const float*)d_in[12];

  int n  = in_sizes[2];
  int nE = in_sizes[1] / 2;
  const int* src = ei;
  const int* dst = ei + nE;
  int nbuk = (n + 127) >> 7;  // 128-node dst buckets

  // Workspace (~66 MB). Tables are (n+4) rows: row n is the shared zero row
  // used by csr pad entries. csr is fixed-stride: n*NSLOT ints.
  size_t T = (size_t)(n + 4) * 128;  // table stride in bytes
  uint8_t*  tab0 = (uint8_t*)d_ws;                      // fp8 table A
  uint8_t*  tab1 = tab0 + T;                            // fp8 table B
  float* dinv    = (float*)(tab1 + T);
  int*   deg     = (int*)(dinv + n);
  int*   bcur    = deg + n;                             // [nbuk*8*16] padded
  int*   csr     = bcur + nbuk * 8 * 16;                // [n*NSLOT]
  uint32_t* ebuf = (uint32_t*)(csr + (size_t)n * NSLOT);  // [nbuk*8*SUBCAP]
  uint16_t* WT   = (uint16_t*)(ebuf + (size_t)nbuk * 8 * SUBCAP);
  float* pool    = (float*)(WT + 3 * 16384);
  float* out     = (float*)d_out;

  hipMemsetAsync(bcur, 0, (size_t)nbuk * 8 * 16 * sizeof(int), stream);
  bucket_scatter<<<(nE + TILE - 1) / TILE, 256, 0, stream>>>(src, dst, bcur, ebuf, nE, nbuk);
  bucket_build<<<nbuk, 256, 0, stream>>>(ebuf, bcur, deg, dinv, csr,
                                         W1, W2, W3, WT, pool,
                                         (uint32_t*)(tab0 + (size_t)n * 128),
                                         (uint32_t*)(tab1 + (size_t)n * 128),
                                         n, nbuk);

  int gfb = (n + 15) / 16;  // fused blocks: 16 nodes each
  gemm_mfma<true><<<(n + 63) / 64, 256, 0, stream>>>(nullptr, x, WT, dinv, tab0, n);
  gather_gemm<false><<<gfb, 512, 0, stream>>>(tab0, csr, deg, dinv, b1,
                                              WT + 16384, tab1, nullptr, nullptr, n);
  gather_gemm<false><<<gfb, 512, 0, stream>>>(tab1, csr, deg, dinv, b2,
                                              WT + 32768, tab0, nullptr, nullptr, n);
  gather_gemm<true><<<gfb, 512, 0, stream>>>(tab0, csr, deg, dinv, b3,
                                             nullptr, nullptr, batch, pool, n);
  classifier_kernel<<<64, 64, 0, stream>>>(pool, batch, Wc1, bc1, Wc2, bc2, out, n);
}